// Round 3
// baseline (1118.729 us; speedup 1.0000x reference)
//
#include <hip/hip_runtime.h>
#include <hip/hip_bf16.h>

#define NN 100000
#define NE 1600000
#define DD 128
#define SD 384
#define BB 1024
#define ECAP 262144
#define L1CAP 49152

typedef unsigned int u32;
typedef unsigned short u16;

__device__ __forceinline__ float bf2f(u16 x){ return __uint_as_float(((u32)x) << 16); }
__device__ __forceinline__ u16 f2bf(float f){
  u32 u = __float_as_uint(f);
  return (u16)((u + 0x7FFFu + ((u >> 16) & 1u)) >> 16);
}

// ---- s1p/s2p = s @ w_proj (fp32 in/out) -----------------------------------
__global__ __launch_bounds__(128) void k_proj(const float* __restrict__ s1, const float* __restrict__ s2,
                                              const float* __restrict__ wp,
                                              float* __restrict__ s1p, float* __restrict__ s2p){
  __shared__ float srow[SD];
  int t = threadIdx.x;
  for (int task = blockIdx.x; task < 2*BB; task += gridDim.x){
    const float* s = (task < BB) ? s1 : s2;
    float* sp      = (task < BB) ? s1p : s2p;
    int row = task & (BB-1);
    __syncthreads();
    for (int k = t; k < SD; k += 128) srow[k] = s[row*SD + k];
    __syncthreads();
    float acc = 0.f;
    #pragma unroll 4
    for (int k = 0; k < SD; ++k) acc += srow[k] * wp[k*DD + t];
    sp[row*DD + t] = acc;
  }
}

// ---- mark selected nodes (S = idx1 ∪ idx2), claim slots, owner priority ---
// numpy scatter semantics: x[idx1]=s1p then x[idx2]=s2p, later wins -> max j (idx2: B+j)
__global__ void k_prep(const int* __restrict__ idx1, const int* __restrict__ idx2,
                       int* __restrict__ owner, int* __restrict__ slot1, int* __restrict__ slotS,
                       int* __restrict__ cnt, int* __restrict__ list1){
  int j = blockIdx.x*blockDim.x + threadIdx.x;
  if (j >= 2*BB) return;
  int n = (j < BB) ? idx1[j] : idx2[j - BB];
  atomicMax(&owner[n], j);
  if (atomicCAS(&slotS[n], -1, -2) == -1){ int s = atomicAdd(&cnt[1], 1); slotS[n] = s; }
  if (atomicCAS(&slot1[n], -1, -2) == -1){
    int s = atomicAdd(&cnt[0], 1);
    if (s < L1CAP){ list1[s] = n; slot1[n] = s; } else slot1[n] = -3;
  }
}

// ---- full edge scan: degree accumulation + collect edges with dst in S ----
__global__ __launch_bounds__(256) void k_scan1(const int* __restrict__ esrc, const int* __restrict__ edst,
                       const float* __restrict__ ew, float* __restrict__ deg,
                       const int* __restrict__ slotS, int* __restrict__ slot1,
                       int* __restrict__ cnt, int* __restrict__ list1,
                       int* __restrict__ eS, int* __restrict__ eD, float* __restrict__ eWl){
  int stride = gridDim.x*blockDim.x;
  for (int e = blockIdx.x*blockDim.x + threadIdx.x; e < NE; e += stride){
    int s = esrc[e], d = edst[e];
    float w = ew[e];
    atomicAdd(&deg[d], w);
    if (slotS[d] >= 0){
      int k = atomicAdd(&cnt[2], 1);
      if (k < ECAP){ eS[k] = s; eD[k] = d; eWl[k] = w; }
      if (atomicCAS(&slot1[s], -1, -2) == -1){
        int q = atomicAdd(&cnt[0], 1);
        if (q < L1CAP){ list1[q] = s; slot1[s] = q; } else slot1[s] = -3;
      }
    }
  }
}

// ---- dinv = rsqrt(deg + 1)  (+1 = self loop weight) -----------------------
__global__ void k_dinv(const float* __restrict__ deg, float* __restrict__ dinv){
  int n = blockIdx.x*blockDim.x + threadIdx.x;
  if (n < NN) dinv[n] = rsqrtf(deg[n] + 1.0f);
}

// ---- zero only the agg1 rows that will be used ----------------------------
__global__ void k_zero1(float* __restrict__ agg1, const int* __restrict__ cnt){
  int n = cnt[0]; if (n > L1CAP) n = L1CAP;
  long total = (long)n * DD;
  long stride = (long)gridDim.x * blockDim.x;
  for (long i = blockIdx.x*(long)blockDim.x + threadIdx.x; i < total; i += stride)
    agg1[i] = 0.f;
}

// ---- layer-1 aggregation: agg1[slot1[dst]] += norm * x[src] ---------------
__global__ __launch_bounds__(256) void k_aggL1(const int* __restrict__ esrc, const int* __restrict__ edst,
    const float* __restrict__ ew, const float* __restrict__ dinv,
    const int* __restrict__ slot1, const int* __restrict__ owner,
    const float* __restrict__ emb, const float* __restrict__ s1p, const float* __restrict__ s2p,
    float* __restrict__ agg1){
  int lane = threadIdx.x & 63;
  int wid  = (blockIdx.x*blockDim.x + threadIdx.x) >> 6;
  int nw   = (gridDim.x*blockDim.x) >> 6;
  for (int e = wid; e < NE; e += nw){
    int d  = edst[e];
    int sl = slot1[d];
    if (sl < 0) continue;
    int s = esrc[e];
    float nrm = dinv[s] * dinv[d] * ew[e];
    int o = owner[s];
    const float* xp = (o < 0) ? (emb + (size_t)s*DD)
                    : (o < BB) ? (s1p + (size_t)o*DD) : (s2p + (size_t)(o-BB)*DD);
    float2 v = *(const float2*)(xp + lane*2);
    float* ap = agg1 + (size_t)sl*DD + lane*2;
    atomicAdd(ap,   nrm*v.x);
    atomicAdd(ap+1, nrm*v.y);
  }
}

// ---- h = relu((agg1 + self) @ w1), bf16; w1 packed bf16 in registers ------
__global__ __launch_bounds__(128) void k_gemm1(const float* __restrict__ agg1, const int* __restrict__ list1,
    const int* __restrict__ cnt, const float* __restrict__ w1, const float* __restrict__ dinv,
    const int* __restrict__ owner, const float* __restrict__ emb,
    const float* __restrict__ s1p, const float* __restrict__ s2p,
    u16* __restrict__ hbuf){
  __shared__ float row[DD];
  int t = threadIdx.x;
  u32 wreg[DD/2];
  #pragma unroll
  for (int i = 0; i < DD/2; ++i){
    u32 lo = f2bf(w1[(2*i)*DD + t]);
    u32 hi = f2bf(w1[(2*i+1)*DD + t]);
    wreg[i] = lo | (hi << 16);
  }
  int n1 = cnt[0]; if (n1 > L1CAP) n1 = L1CAP;
  for (int sl = blockIdx.x; sl < n1; sl += gridDim.x){
    int n = list1[sl];
    int o = owner[n];
    float di = dinv[n];
    float xv;
    if (o < 0) xv = emb[(size_t)n*DD + t];
    else if (o < BB) xv = s1p[(size_t)o*DD + t];
    else xv = s2p[(size_t)(o-BB)*DD + t];
    __syncthreads();
    row[t] = agg1[(size_t)sl*DD + t] + di*di*xv;
    __syncthreads();
    float acc = 0.f;
    #pragma unroll
    for (int i = 0; i < DD/2; ++i){
      float2 rv = *(const float2*)&row[2*i];
      u32 w = wreg[i];
      acc += rv.x * bf2f((u16)w);
      acc += rv.y * bf2f((u16)(w >> 16));
    }
    hbuf[(size_t)sl*DD + t] = f2bf(fmaxf(acc, 0.f));
  }
}

// ---- layer-2 aggregation over collected edges only ------------------------
__global__ __launch_bounds__(256) void k_aggL2(const int* __restrict__ eS, const int* __restrict__ eD,
    const float* __restrict__ eWl, const int* __restrict__ cnt,
    const float* __restrict__ dinv, const int* __restrict__ slot1, const int* __restrict__ slotS,
    const u16* __restrict__ hbuf, float* __restrict__ agg2){
  int lane = threadIdx.x & 63;
  int wid  = (blockIdx.x*blockDim.x + threadIdx.x) >> 6;
  int nw   = (gridDim.x*blockDim.x) >> 6;
  int ne = cnt[2]; if (ne > ECAP) ne = ECAP;
  for (int e = wid; e < ne; e += nw){
    int s = eS[e], d = eD[e];
    int sl = slot1[s];
    if (sl < 0) continue;     // safety (cap overflow path)
    float nrm = dinv[s] * dinv[d] * eWl[e];
    u32 p = *(const u32*)(hbuf + (size_t)sl*DD + lane*2);
    float* ap = agg2 + (size_t)slotS[d]*DD + lane*2;
    atomicAdd(ap,   nrm*bf2f((u16)p));
    atomicAdd(ap+1, nrm*bf2f((u16)(p >> 16)));
  }
}

// ---- x_g = (agg2 + self) @ w2 ; out = 0.7*sp + 0.3*x_g (FP32 out) ---------
__global__ __launch_bounds__(128) void k_final(const int* __restrict__ idx1, const int* __restrict__ idx2,
    const float* __restrict__ s1p, const float* __restrict__ s2p,
    const float* __restrict__ agg2, const int* __restrict__ slot1, const int* __restrict__ slotS,
    const float* __restrict__ dinv, const u16* __restrict__ hbuf, const float* __restrict__ w2,
    float* __restrict__ out){
  __shared__ float row[DD];
  int t = threadIdx.x;
  u32 wreg[DD/2];
  #pragma unroll
  for (int i = 0; i < DD/2; ++i){
    u32 lo = f2bf(w2[(2*i)*DD + t]);
    u32 hi = f2bf(w2[(2*i+1)*DD + t]);
    wreg[i] = lo | (hi << 16);
  }
  for (int j = blockIdx.x; j < 2*BB; j += gridDim.x){
    int n = (j < BB) ? idx1[j] : idx2[j - BB];
    float di = dinv[n];
    int sl = slot1[n];
    float hv = (sl >= 0) ? bf2f(hbuf[(size_t)sl*DD + t]) : 0.f;
    __syncthreads();
    row[t] = agg2[(size_t)slotS[n]*DD + t] + di*di*hv;
    __syncthreads();
    float acc = 0.f;
    #pragma unroll
    for (int i = 0; i < DD/2; ++i){
      float2 rv = *(const float2*)&row[2*i];
      u32 w = wreg[i];
      acc += rv.x * bf2f((u16)w);
      acc += rv.y * bf2f((u16)(w >> 16));
    }
    float sp = (j < BB) ? s1p[(size_t)j*DD + t] : s2p[(size_t)(j-BB)*DD + t];
    out[(size_t)j*DD + t] = 0.7f*sp + 0.3f*acc;
  }
}

extern "C" void kernel_launch(void* const* d_in, const int* in_sizes, int n_in,
                              void* d_out, int out_size, void* d_ws, size_t ws_size,
                              hipStream_t stream){
  const float* emb  = (const float*)d_in[0];
  const float* s1   = (const float*)d_in[1];
  const float* s2   = (const float*)d_in[2];
  const float* wp   = (const float*)d_in[3];
  const float* w1   = (const float*)d_in[4];
  const float* w2   = (const float*)d_in[5];
  const int* idx1 = (const int*)d_in[6];
  const int* idx2 = (const int*)d_in[7];
  const int* eidx = (const int*)d_in[8];
  const float* ew   = (const float*)d_in[9];
  const int* esrc = eidx;
  const int* edst = eidx + NE;

  char* ws = (char*)d_ws;
  size_t off = 0;
  auto A = [&](size_t b){ size_t r = off; off += (b + 255) & ~(size_t)255; return r; };
  float* deg  = (float*)(ws + A((size_t)NN*4));
  float* dinv = (float*)(ws + A((size_t)NN*4));
  int* owner  = (int*)  (ws + A((size_t)NN*4));
  int* slot1  = (int*)  (ws + A((size_t)NN*4));
  int* slotS  = (int*)  (ws + A((size_t)NN*4));
  int* list1  = (int*)  (ws + A((size_t)L1CAP*4));
  int* cnt    = (int*)  (ws + A(256));
  int* eS     = (int*)  (ws + A((size_t)ECAP*4));
  int* eD     = (int*)  (ws + A((size_t)ECAP*4));
  float* eWl  = (float*)(ws + A((size_t)ECAP*4));
  float* s1p  = (float*)(ws + A((size_t)BB*DD*4));
  float* s2p  = (float*)(ws + A((size_t)BB*DD*4));
  float* agg1 = (float*)(ws + A((size_t)L1CAP*DD*4));
  u16*   hbuf = (u16*)  (ws + A((size_t)L1CAP*DD*2));
  float* agg2 = (float*)(ws + A((size_t)2*BB*DD*4));
  (void)in_sizes; (void)n_in; (void)out_size;
  if (ws_size < off) return;   // diagnostic: leaves out == 0 (absmax ~= 3.0)

  hipMemsetAsync(deg,   0,    (size_t)NN*4, stream);
  hipMemsetAsync(owner, 0xFF, (size_t)NN*4, stream);   // -1
  hipMemsetAsync(slot1, 0xFF, (size_t)NN*4, stream);   // -1
  hipMemsetAsync(slotS, 0xFF, (size_t)NN*4, stream);   // -1
  hipMemsetAsync(cnt,   0,    256, stream);
  hipMemsetAsync(agg2,  0,    (size_t)2*BB*DD*4, stream);

  k_proj <<<512, 128, 0, stream>>>(s1, s2, wp, s1p, s2p);
  k_prep <<<8, 256, 0, stream>>>(idx1, idx2, owner, slot1, slotS, cnt, list1);
  k_scan1<<<2048, 256, 0, stream>>>(esrc, edst, ew, deg, slotS, slot1, cnt, list1, eS, eD, eWl);
  k_dinv <<<(NN+255)/256, 256, 0, stream>>>(deg, dinv);
  k_zero1<<<1024, 256, 0, stream>>>(agg1, cnt);
  k_aggL1<<<2048, 256, 0, stream>>>(esrc, edst, ew, dinv, slot1, owner, emb, s1p, s2p, agg1);
  k_gemm1<<<2048, 128, 0, stream>>>(agg1, list1, cnt, w1, dinv, owner, emb, s1p, s2p, hbuf);
  k_aggL2<<<512, 256, 0, stream>>>(eS, eD, eWl, cnt, dinv, slot1, slotS, hbuf, agg2);
  k_final<<<256, 128, 0, stream>>>(idx1, idx2, s1p, s2p, agg2, slot1, slotS, dinv, hbuf, w2, (float*)d_out);
}